// Round 5
// baseline (1473.670 us; speedup 1.0000x reference)
//
#include <hip/hip_runtime.h>

// LSTM: B=512, T=1000, IN=39, H=64, OUT=48, gate order i,f,g,o.
// One block per row; thread = gate (256 thr). R5 redesign:
//  - Weights register-resident: asm pins (no remat) + __launch_bounds__(256,2)
//    (min 2 waves/EU -> VGPR budget 256; R4's 88-VGPR spill came from the
//    default high-occupancy budget after I dropped the ",2").
//  - LDS-BW wall removed (was 416 B/thread/step b128 broadcast = ~2500cyc/CU,
//    matching the observed 1055us): x_t is block-uniform -> scalar s_load
//    (SMEM pipe); h-dot uses ds_read_b32 (h distributed, 4B/lane) +
//    v_readlane -> v_fmac(v,s,v) on the VALU crossbar. LDS now only carries
//    act[] (b32) and the out-proj h reads (4 b128).

#define BB 512
#define TT 1000
#define INF 39
#define HH 64
#define OUTF 48
#define G4 (4 * HH)

#define Q10(M) M(0) M(1) M(2) M(3) M(4) M(5) M(6) M(7) M(8) M(9)
#define Q16(M) M(0) M(1) M(2) M(3) M(4) M(5) M(6) M(7) \
               M(8) M(9) M(10) M(11) M(12) M(13) M(14) M(15)

#define PIN4(v) asm volatile("" : "+v"(v.x), "+v"(v.y), "+v"(v.z), "+v"(v.w));

__global__ __launch_bounds__(256, 2) void lstm_fused_kernel(
    const float* __restrict__ x,      // [B,T,IN]
    const float* __restrict__ W_ih,   // [4H, IN]
    const float* __restrict__ W_hh,   // [4H, H]
    const float* __restrict__ b_ih,   // [4H]
    const float* __restrict__ b_hh,   // [4H]
    const float* __restrict__ W_out,  // [OUT, H]
    const float* __restrict__ b_out,  // [OUT]
    float* __restrict__ out)          // [B,T,OUT]
{
    const int b = blockIdx.x;
    const int tid = threadIdx.x;          // gate index in [0,256)
    const int lane = tid & 63;

    __shared__ float hs[HH];              // h_t (written by tid<64)
    __shared__ float act[G4];             // gate activations

    // ---- one-time: weights into NAMED, PINNED registers ----
    const float* wih_ptr = W_ih + tid * INF;
#define LOAD_IH4(q) float4 wiq##q; \
    wiq##q.x = wih_ptr[4*(q)]; \
    wiq##q.y = (4*(q)+1 < INF) ? wih_ptr[4*(q)+1] : 0.f; \
    wiq##q.z = (4*(q)+2 < INF) ? wih_ptr[4*(q)+2] : 0.f; \
    wiq##q.w = (4*(q)+3 < INF) ? wih_ptr[4*(q)+3] : 0.f;
    Q10(LOAD_IH4)

    const float4* wh4p = (const float4*)(W_hh + tid * HH);
#define LOAD_HH4(i) float4 wh##i = wh4p[i];
    Q16(LOAD_HH4)

    float bias = b_ih[tid] + b_hh[tid];

    const int o = tid >> 2;               // out-proj: tid<192 -> (o, p)
    const int p = tid & 3;
    float4 wo0, wo1, wo2, wo3;
    float bo = 0.f;
    if (tid < 4 * OUTF) {
        const float4* wop = (const float4*)(W_out + o * HH + p * 16);
        wo0 = wop[0]; wo1 = wop[1]; wo2 = wop[2]; wo3 = wop[3];
        bo = b_out[o];
    } else {
        wo0 = wo1 = wo2 = wo3 = make_float4(0.f, 0.f, 0.f, 0.f);
    }

#define PIN_IH(q) PIN4(wiq##q)
    Q10(PIN_IH)
#define PIN_HH(i) PIN4(wh##i)
    Q16(PIN_HH)
    PIN4(wo0) PIN4(wo1) PIN4(wo2) PIN4(wo3)
    asm volatile("" : "+v"(bias), "+v"(bo));

    float c = 0.f;                        // cell state, owned by tid<64
    const size_t x_base = (size_t)b * TT * INF;
    const size_t out_base = (size_t)b * TT * OUTF;

    if (tid < HH) hs[tid] = 0.f;
    const int gate_type = tid >> 6;       // wave-uniform: 0=i,1=f,2=g,3=o
    __syncthreads();                      // hs = h_{-1} = 0

    const float4* hs4 = (const float4*)hs;

    for (int t = 0; t < TT; ++t) {
        // h_{t-1} distributed: lane k holds h_k (4B/lane, conflict-free)
        const int hbits = __float_as_int(hs[lane]);

        // x_t is block-uniform -> scalar loads (SMEM pipe), k is constant
        const float* xp = x + x_base + (size_t)t * INF;
#define XF(k) ((k) < INF ? xp[k] : 0.f)

        float a0 = bias, a1 = 0.f, a2 = 0.f, a3 = 0.f;
        // ---- h . W_hh_row via readlane (uniform scalar) x resident weight ----
#define HFMA(i) { \
        a0 += __int_as_float(__builtin_amdgcn_readlane(hbits, 4*(i)+0)) * wh##i.x; \
        a1 += __int_as_float(__builtin_amdgcn_readlane(hbits, 4*(i)+1)) * wh##i.y; \
        a2 += __int_as_float(__builtin_amdgcn_readlane(hbits, 4*(i)+2)) * wh##i.z; \
        a3 += __int_as_float(__builtin_amdgcn_readlane(hbits, 4*(i)+3)) * wh##i.w; }
        Q16(HFMA)
        // ---- x . W_ih_row via scalar-loaded x (s_load) ----
#define XFMA(q) { \
        a0 += XF(4*(q)+0) * wiq##q.x; \
        a1 += XF(4*(q)+1) * wiq##q.y; \
        a2 += XF(4*(q)+2) * wiq##q.z; \
        a3 += XF(4*(q)+3) * wiq##q.w; }
        Q10(XFMA)
        const float acc = (a0 + a1) + (a2 + a3);

        float a;
        if (gate_type == 2) {             // tanh for g-gate (wave-uniform)
            a = 2.f / (1.f + __expf(-2.f * acc)) - 1.f;
        } else {                          // sigmoid for i,f,o
            a = 1.f / (1.f + __expf(-acc));
        }
        act[tid] = a;
        __syncthreads();                  // A: act ready; hs reads done

        if (tid < HH) {
            const float ig = act[tid];
            const float fg = act[HH + tid];
            const float gg = act[2 * HH + tid];
            const float og = act[3 * HH + tid];
            c = fg * c + ig * gg;
            const float th = 2.f / (1.f + __expf(-2.f * c)) - 1.f;
            hs[tid] = og * th;
        }
        __syncthreads();                  // B: hs = h_t

        // ---- output projection y_t = sigmoid(h_t . W_out_row + b) ----
        if (tid < 4 * OUTF) {
            const float4 h0 = hs4[p * 4 + 0];
            const float4 h1 = hs4[p * 4 + 1];
            const float4 h2 = hs4[p * 4 + 2];
            const float4 h3 = hs4[p * 4 + 3];
            float s0 = h0.x * wo0.x + h0.y * wo0.y + h0.z * wo0.z + h0.w * wo0.w;
            float s1 = h1.x * wo1.x + h1.y * wo1.y + h1.z * wo1.z + h1.w * wo1.w;
            float s2 = h2.x * wo2.x + h2.y * wo2.y + h2.z * wo2.z + h2.w * wo2.w;
            float s3 = h3.x * wo3.x + h3.y * wo3.y + h3.z * wo3.z + h3.w * wo3.w;
            float s = (s0 + s1) + (s2 + s3);
            s += __shfl_xor(s, 1, 64);
            s += __shfl_xor(s, 2, 64);
            if (p == 0) {
                const float y = 1.f / (1.f + __expf(-(s + bo)));
                __builtin_nontemporal_store(y, &out[out_base + (size_t)t * OUTF + o]);
            }
        }
    }
}

extern "C" void kernel_launch(void* const* d_in, const int* in_sizes, int n_in,
                              void* d_out, int out_size, void* d_ws, size_t ws_size,
                              hipStream_t stream) {
    const float* x     = (const float*)d_in[0];
    const float* W_ih  = (const float*)d_in[1];
    const float* W_hh  = (const float*)d_in[2];
    const float* b_ih  = (const float*)d_in[3];
    const float* b_hh  = (const float*)d_in[4];
    const float* W_out = (const float*)d_in[5];
    const float* b_out = (const float*)d_in[6];
    float* out = (float*)d_out;

    lstm_fused_kernel<<<dim3(BB), dim3(G4), 0, stream>>>(
        x, W_ih, W_hh, b_ih, b_hh, W_out, b_out, out);
}

// Round 6
// 1432.745 us; speedup vs baseline: 1.0286x; 1.0286x over previous
//
#include <hip/hip_runtime.h>
#include <hip/hip_fp16.h>

// LSTM: B=512, T=1000, IN=39, H=64, OUT=48, gate order i,f,g,o.
// One block per row. R6 redesign on the validated cost model
// (R3 2530 cyc/step == 26 b128 * 12cyc * 8 waves LDS return BW):
//  - Occupancy pinned with amdgpu_waves_per_eu(2,2) ALONE (launch_bounds'
//    implicit waves-per-eu clobbered it in R4; its 2nd arg is only a MIN in
//    R5). Grid gives 2 blocks/CU = 2 waves/EU, so capping max at 2 makes
//    spilling worthless -> ~160 weight floats stay register-resident.
//  - x-dot via scalar loads (block-uniform address -> s_load; v_fmac v,s,v
//    broadcasts for free). Zero LDS for x.
//  - h stored in LDS as f16 ping-pong (halves h-broadcast bytes: 8 b128).
//  - Quad-gate mapping tid=4j+g: i/f/g/o exchanged with 3 in-quad shfl_xor
//    (DPP), no act[] LDS, ONE barrier/step.

#define BB 512
#define TT 1000
#define INF 39
#define HH 64
#define OUTF 48

#define Q10(M) M(0) M(1) M(2) M(3) M(4) M(5) M(6) M(7) M(8) M(9)
#define Q16(M) M(0) M(1) M(2) M(3) M(4) M(5) M(6) M(7) \
               M(8) M(9) M(10) M(11) M(12) M(13) M(14) M(15)

#define PIN4(v) asm volatile("" : "+v"(v.x), "+v"(v.y), "+v"(v.z), "+v"(v.w));

__device__ __forceinline__ float2 h2f(unsigned int u) {
    __half2 h = *reinterpret_cast<const __half2*>(&u);
    return __half22float2(h);
}

__global__ __attribute__((amdgpu_flat_work_group_size(256, 256)))
__attribute__((amdgpu_waves_per_eu(2, 2)))
void lstm_fused_kernel(
    const float* __restrict__ x,      // [B,T,IN]
    const float* __restrict__ W_ih,   // [4H, IN]
    const float* __restrict__ W_hh,   // [4H, H]
    const float* __restrict__ b_ih,   // [4H]
    const float* __restrict__ b_hh,   // [4H]
    const float* __restrict__ W_out,  // [OUT, H]
    const float* __restrict__ b_out,  // [OUT]
    float* __restrict__ out)          // [B,T,OUT]
{
    const int b = blockIdx.x;
    const int tid = threadIdx.x;
    const int j = tid >> 2;               // h index 0..63
    const int g = tid & 3;                // gate 0=i,1=f,2=g,3=o
    const int row = g * HH + j;           // weight row (gate-major)

    __shared__ __align__(16) __half hbuf[2][HH];   // h ping-pong, f16

    // ---- one-time: weights into registers ----
    const float* wih_ptr = W_ih + row * INF;
#define LOAD_IH4(q) float4 wiq##q; \
    wiq##q.x = wih_ptr[4*(q)]; \
    wiq##q.y = (4*(q)+1 < INF) ? wih_ptr[4*(q)+1] : 0.f; \
    wiq##q.z = (4*(q)+2 < INF) ? wih_ptr[4*(q)+2] : 0.f; \
    wiq##q.w = (4*(q)+3 < INF) ? wih_ptr[4*(q)+3] : 0.f;
    Q10(LOAD_IH4)

    const float4* wh4p = (const float4*)(W_hh + row * HH);
#define LOAD_HH4(i) float4 wh##i = wh4p[i];
    Q16(LOAD_HH4)

    float bias = b_ih[row] + b_hh[row];

    // out-proj slice: tid<192 -> (o = tid>>2, p = tid&3), 16 weights
    const int o = tid >> 2;
    const int p = tid & 3;
    float4 wo0, wo1, wo2, wo3;
    float bo = 0.f;
    if (tid < 4 * OUTF) {
        const float4* wop = (const float4*)(W_out + o * HH + p * 16);
        wo0 = wop[0]; wo1 = wop[1]; wo2 = wop[2]; wo3 = wop[3];
        bo = b_out[o];
    } else {
        wo0 = wo1 = wo2 = wo3 = make_float4(0.f, 0.f, 0.f, 0.f);
    }

#define PIN_IH(q) PIN4(wiq##q)
    Q10(PIN_IH)
#define PIN_HH(i) PIN4(wh##i)
    Q16(PIN_HH)
    PIN4(wo0) PIN4(wo1) PIN4(wo2) PIN4(wo3)
    asm volatile("" : "+v"(bias), "+v"(bo));

    float c = 0.f;                        // cell state, redundant per quad
    const size_t x_base = (size_t)b * TT * INF;
    const size_t out_base = (size_t)b * TT * OUTF;

    if (tid < HH) hbuf[0][tid] = __float2half(0.f);
    __syncthreads();

    for (int t = 0; t < TT; ++t) {
        const int cur = t & 1;
        const int nxt = cur ^ 1;
        const float* xp = x + x_base + (size_t)t * INF;   // uniform -> s_load
        const uint4* hb = (const uint4*)(&hbuf[cur][0]);

        float a0 = bias, a1 = 0.f, a2 = 0.f, a3 = 0.f;

        // ---- h . W_hh_row : f16 LDS broadcast, 8 x b128 ----
#define HQ(q, e, oo) { const uint4 u = hb[q]; \
        const float2 f0 = h2f(u.x), f1 = h2f(u.y), f2 = h2f(u.z), f3 = h2f(u.w); \
        a0 += f0.x * wh##e.x;  a1 += f0.y * wh##e.y; \
        a2 += f1.x * wh##e.z;  a3 += f1.y * wh##e.w; \
        a0 += f2.x * wh##oo.x; a1 += f2.y * wh##oo.y; \
        a2 += f3.x * wh##oo.z; a3 += f3.y * wh##oo.w; }
        HQ(0,0,1) HQ(1,2,3) HQ(2,4,5) HQ(3,6,7)
        HQ(4,8,9) HQ(5,10,11) HQ(6,12,13) HQ(7,14,15)

        // ---- x . W_ih_row : scalar x (SGPR operand), zero LDS ----
#define XFMA(q) { \
        a0 += xp[4*(q)] * wiq##q.x; \
        if (4*(q)+1 < INF) a1 += xp[4*(q)+1] * wiq##q.y; \
        if (4*(q)+2 < INF) a2 += xp[4*(q)+2] * wiq##q.z; \
        if (4*(q)+3 < INF) a3 += xp[4*(q)+3] * wiq##q.w; }
        Q10(XFMA)
        const float acc = (a0 + a1) + (a2 + a3);

        // ---- activation (g-gate tanh via sigmoid identity, branchless) ----
        const bool isg = (g == 2);
        const float z = isg ? 2.f * acc : acc;
        const float s = 1.f / (1.f + __expf(-z));
        const float a = isg ? (2.f * s - 1.f) : s;

        // ---- quad exchange: act_q = v_{g^q} ----
        const float v1 = __shfl_xor(a, 1, 64);
        const float v2 = __shfl_xor(a, 2, 64);
        const float v3 = __shfl_xor(a, 3, 64);
        const int g1 = g & 1, g2 = g & 2;
        const float t01 = g1 ? v1 : a;
        const float u01 = g1 ? a  : v1;
        const float t23 = g1 ? v3 : v2;
        const float u23 = g1 ? v2 : v3;
        const float i_act = g2 ? t23 : t01;
        const float f_act = g2 ? u23 : u01;
        const float g_act = g2 ? t01 : t23;
        const float o_act = g2 ? u01 : u23;

        // ---- c/h update (redundant across quad lanes) ----
        c = f_act * c + i_act * g_act;
        const float th = 2.f / (1.f + __expf(-2.f * c)) - 1.f;
        const float h = o_act * th;
        if (g == 0) hbuf[nxt][j] = __float2half(h);
        __syncthreads();                  // h_t visible to all

        // ---- output projection y = sigmoid(h_t . W_out_row + b) ----
        if (tid < 4 * OUTF) {
            const uint4* hn = (const uint4*)(&hbuf[nxt][0]);
            const uint4 u0 = hn[p * 2];
            const uint4 u1 = hn[p * 2 + 1];
            const float2 e0 = h2f(u0.x), e1 = h2f(u0.y), e2 = h2f(u0.z), e3 = h2f(u0.w);
            const float2 e4 = h2f(u1.x), e5 = h2f(u1.y), e6 = h2f(u1.z), e7 = h2f(u1.w);
            float s0 = e0.x * wo0.x + e0.y * wo0.y + e1.x * wo0.z + e1.y * wo0.w;
            float s1 = e2.x * wo1.x + e2.y * wo1.y + e3.x * wo1.z + e3.y * wo1.w;
            float s2 = e4.x * wo2.x + e4.y * wo2.y + e5.x * wo2.z + e5.y * wo2.w;
            float s3 = e6.x * wo3.x + e6.y * wo3.y + e7.x * wo3.z + e7.y * wo3.w;
            float sum = (s0 + s1) + (s2 + s3);
            sum += __shfl_xor(sum, 1, 64);
            sum += __shfl_xor(sum, 2, 64);
            if (p == 0) {
                const float y = 1.f / (1.f + __expf(-(sum + bo)));
                __builtin_nontemporal_store(y, &out[out_base + (size_t)t * OUTF + o]);
            }
        }
    }
}

extern "C" void kernel_launch(void* const* d_in, const int* in_sizes, int n_in,
                              void* d_out, int out_size, void* d_ws, size_t ws_size,
                              hipStream_t stream) {
    const float* x     = (const float*)d_in[0];
    const float* W_ih  = (const float*)d_in[1];
    const float* W_hh  = (const float*)d_in[2];
    const float* b_ih  = (const float*)d_in[3];
    const float* b_hh  = (const float*)d_in[4];
    const float* W_out = (const float*)d_in[5];
    const float* b_out = (const float*)d_in[6];
    float* out = (float*)d_out;

    lstm_fused_kernel<<<dim3(BB), dim3(256), 0, stream>>>(
        x, W_ih, W_hh, b_ih, b_hh, W_out, b_out, out);
}